// Round 1
// baseline (2140.758 us; speedup 1.0000x reference)
//
#include <hip/hip_runtime.h>
#include <hip/hip_bf16.h>

#define BB 512
#define SS 2048
#define VV 29
#define HH 128

__device__ __forceinline__ float fast_tanh(float z) {
    // tanh(z) = sign(z) * (1 - 2e/(1+e)),  e = exp(-2|z|)
    float az = fabsf(z);
    float e  = __expf(-2.0f * az);
    float r  = 1.0f - 2.0f * e * __builtin_amdgcn_rcpf(1.0f + e);
    return copysignf(r, z);
}

__global__ __launch_bounds__(128, 1) void rnn_fused(
    const float* __restrict__ x,      // (B,S,V)
    const float* __restrict__ We_ih,  // (H,V)
    const float* __restrict__ We_hh,  // (H,H)
    const float* __restrict__ be_ih,  // (H)
    const float* __restrict__ be_hh,  // (H)
    const float* __restrict__ Wd_ih,  // (V,H)
    const float* __restrict__ Wd_hh,  // (V,V)
    const float* __restrict__ bd_ih,  // (V)
    const float* __restrict__ bd_hh,  // (V)
    float* __restrict__ out)          // (B,S,V)
{
    const int b = blockIdx.x;
    const int i = threadIdx.x;  // 0..127

    __shared__ float hbuf[2][HH];
    __shared__ float xbuf[2][VV];
    __shared__ float hd[2][32];

    // ---- encoder weights to registers ----
    float w[HH];
    const float* wrow = We_hh + i * HH;
    #pragma unroll
    for (int j = 0; j < HH; ++j) w[j] = wrow[j];

    float wih[VV];
    const float* wi = We_ih + i * VV;
    #pragma unroll
    for (int j = 0; j < VV; ++j) wih[j] = wi[j];

    const float bias = be_ih[i] + be_hh[i];

    // init h = 0, stage x[b,0,:]
    const float* xb = x + (size_t)b * SS * VV;
    hbuf[0][i] = 0.0f;
    if (i < VV) xbuf[0][i] = xb[i];
    __syncthreads();

    // ---- encoder scan ----
    int cur = 0;
    for (int t = 0; t < SS; ++t) {
        // prefetch next x row (latency hidden under the matvec)
        float xnext = 0.0f;
        if (i < VV && t + 1 < SS) xnext = xb[(t + 1) * VV + i];

        float acc = bias;
        #pragma unroll
        for (int j = 0; j < VV; ++j) acc += wih[j] * xbuf[cur][j];

        float a0 = 0.f, a1 = 0.f, a2 = 0.f, a3 = 0.f;
        #pragma unroll
        for (int j = 0; j < HH; j += 4) {
            a0 += w[j + 0] * hbuf[cur][j + 0];
            a1 += w[j + 1] * hbuf[cur][j + 1];
            a2 += w[j + 2] * hbuf[cur][j + 2];
            a3 += w[j + 3] * hbuf[cur][j + 3];
        }
        acc += (a0 + a1) + (a2 + a3);

        float hn = fast_tanh(acc);
        hbuf[cur ^ 1][i] = hn;
        if (i < VV && t + 1 < SS) xbuf[cur ^ 1][i] = xnext;
        __syncthreads();
        cur ^= 1;
    }
    // encoded vector now in hbuf[cur][0..127]

    // ---- decoder init ----
    float wd[VV];
    float dec_in = 0.0f;
    if (i < VV) {
        const float* wdr = Wd_hh + i * VV;
        #pragma unroll
        for (int j = 0; j < VV; ++j) wd[j] = wdr[j];
        float di = bd_ih[i] + bd_hh[i];
        const float* wdi = Wd_ih + i * HH;
        #pragma unroll
        for (int j = 0; j < HH; ++j) di += wdi[j] * hbuf[cur][j];
        dec_in = di;
    }
    if (i < 32) { hd[0][i] = 0.0f; hd[1][i] = 0.0f; }
    __syncthreads();

    // ---- decoder scan ----
    float* ob = out + (size_t)b * SS * VV;
    int c2 = 0;
    for (int t = 0; t < SS; ++t) {
        if (i < VV) {
            float acc = dec_in;
            float b0 = 0.f, b1 = 0.f;
            #pragma unroll
            for (int j = 0; j < VV - 1; j += 2) {
                b0 += wd[j + 0] * hd[c2][j + 0];
                b1 += wd[j + 1] * hd[c2][j + 1];
            }
            acc += b0 + b1 + wd[VV - 1] * hd[c2][VV - 1];
            float hn = fast_tanh(acc);
            ob[t * VV + i] = hn;
            hd[c2 ^ 1][i] = hn;
        }
        __syncthreads();
        c2 ^= 1;
    }
}

extern "C" void kernel_launch(void* const* d_in, const int* in_sizes, int n_in,
                              void* d_out, int out_size, void* d_ws, size_t ws_size,
                              hipStream_t stream) {
    const float* x     = (const float*)d_in[0];
    const float* We_ih = (const float*)d_in[1];
    const float* We_hh = (const float*)d_in[2];
    const float* be_ih = (const float*)d_in[3];
    const float* be_hh = (const float*)d_in[4];
    const float* Wd_ih = (const float*)d_in[5];
    const float* Wd_hh = (const float*)d_in[6];
    const float* bd_ih = (const float*)d_in[7];
    const float* bd_hh = (const float*)d_in[8];
    float* out = (float*)d_out;

    rnn_fused<<<dim3(BB), dim3(128), 0, stream>>>(
        x, We_ih, We_hh, be_ih, be_hh, Wd_ih, Wd_hh, bd_ih, bd_hh, out);
}

// Round 2
// 1790.894 us; speedup vs baseline: 1.1954x; 1.1954x over previous
//
#include <hip/hip_runtime.h>
#include <hip/hip_bf16.h>

#define BB 512
#define SS 2048
#define VV 29
#define HH 128

__device__ __forceinline__ float fast_tanh(float z) {
    // tanh(z) = sign(z) * (1 - 2e/(1+e)),  e = exp(-2|z|)  -- identical to round-1
    float az = fabsf(z);
    float e  = __expf(-2.0f * az);
    float r  = 1.0f - 2.0f * e * __builtin_amdgcn_rcpf(1.0f + e);
    return copysignf(r, z);
}

// One block per batch row. 256 threads = split-K x2 over the h-dot:
//   thread (i, g): partial_g[i] = sum_{j in g-half} We_hh[i][64g+j] * h[64g+j]
//   g0 also does x-proj v=0..14 + bias; g1 does x-proj v=15..28.
// Two barriers/step (partial exchange, h publish). 2048 waves -> 2 waves/SIMD.
// Decoder: single wave, h in lanes, __shfl broadcast, zero barriers.
__global__ __launch_bounds__(256) void rnn_fused(
    const float* __restrict__ x,      // (B,S,V)
    const float* __restrict__ We_ih,  // (H,V)
    const float* __restrict__ We_hh,  // (H,H)
    const float* __restrict__ be_ih,  // (H)
    const float* __restrict__ be_hh,  // (H)
    const float* __restrict__ Wd_ih,  // (V,H)
    const float* __restrict__ Wd_hh,  // (V,V)
    const float* __restrict__ bd_ih,  // (V)
    const float* __restrict__ bd_hh,  // (V)
    float* __restrict__ out)          // (B,S,V)
{
    const int b   = blockIdx.x;
    const int tid = threadIdx.x;
    const int i   = tid & 127;   // h index
    const int g   = tid >> 7;    // K-half

    __shared__ float hbuf[2][HH];
    __shared__ float xbuf[2][32];   // slots 29..31 stay 0
    __shared__ float part[HH];

    // ---- weights to registers ----
    float w[64];
    const float* wrow = We_hh + i * HH + g * 64;
    #pragma unroll
    for (int j = 0; j < 64; ++j) w[j] = wrow[j];

    const int xv0 = g ? 15 : 0;           // g0: v 0..14, g1: v 15..28
    const int xn  = g ? 14 : 15;
    float wx[15];
    #pragma unroll
    for (int j = 0; j < 15; ++j) wx[j] = (j < xn) ? We_ih[i * VV + xv0 + j] : 0.0f;

    const float bias = (g == 0) ? (be_ih[i] + be_hh[i]) : 0.0f;

    const float* xb = x + (size_t)b * SS * VV;

    if (g == 0) hbuf[0][i] = 0.0f;
    if (tid < 32) {
        xbuf[0][tid] = (tid < VV) ? xb[tid] : 0.0f;
        xbuf[1][tid] = 0.0f;                 // pad slots of buf1 (29..31) stay 0
    }
    __syncthreads();

    // ---- encoder scan, 2x unrolled ping-pong ----
#define ENC_STEP(CUR, NXT, T)                                              \
    {                                                                      \
        float xpre = 0.0f;                                                 \
        {                                                                  \
            int tn = (T) + 1; if (tn >= SS) tn = SS - 1;                   \
            if (g == 0 && i < VV) xpre = xb[tn * VV + i];                  \
        }                                                                  \
        float a0 = 0.f, a1 = 0.f, a2 = 0.f, a3 = 0.f;                      \
        const float* hb = &hbuf[CUR][g * 64];                              \
        _Pragma("unroll")                                                  \
        for (int j = 0; j < 64; j += 4) {                                  \
            a0 += w[j + 0] * hb[j + 0];                                    \
            a1 += w[j + 1] * hb[j + 1];                                    \
            a2 += w[j + 2] * hb[j + 2];                                    \
            a3 += w[j + 3] * hb[j + 3];                                    \
        }                                                                  \
        float accx = bias;                                                 \
        _Pragma("unroll")                                                  \
        for (int j = 0; j < 15; ++j) accx += wx[j] * xbuf[CUR][xv0 + j];   \
        float p = (a0 + a1) + (a2 + a3) + accx;                            \
        if (g) part[i] = p;                                                \
        __syncthreads();                                                   \
        if (g == 0) {                                                      \
            float hn = fast_tanh(p + part[i]);                             \
            hbuf[NXT][i] = hn;                                             \
            if (i < VV) xbuf[NXT][i] = xpre;                               \
        }                                                                  \
        __syncthreads();                                                   \
    }

    for (int t = 0; t < SS; t += 2) {
        ENC_STEP(0, 1, t)
        ENC_STEP(1, 0, t + 1)
    }
    // encoded vector in hbuf[0][0..127]; all threads past final barrier.

    // ---- decoder: single wave (threads 0..63), no barriers ----
    if (tid >= 64) return;
    const int lane = tid;
    const int r = (lane < VV) ? lane : (VV - 1);   // lanes >=29 mirror row 28 (finite garbage)

    // dec_in = encoded @ Wd_ih^T + bd_ih + bd_hh
    float di = bd_ih[r] + bd_hh[r];
    {
        const float* wdi = Wd_ih + r * HH;
        float d0 = 0.f, d1 = 0.f, d2 = 0.f, d3 = 0.f;
        #pragma unroll
        for (int j = 0; j < HH; j += 4) {
            d0 += wdi[j + 0] * hbuf[0][j + 0];
            d1 += wdi[j + 1] * hbuf[0][j + 1];
            d2 += wdi[j + 2] * hbuf[0][j + 2];
            d3 += wdi[j + 3] * hbuf[0][j + 3];
        }
        di += (d0 + d1) + (d2 + d3);
    }

    float wd[VV];
    {
        const float* wdr = Wd_hh + r * VV;
        #pragma unroll
        for (int j = 0; j < VV; ++j) wd[j] = wdr[j];
    }

    float hd = 0.0f;
    float* ob = out + (size_t)b * SS * VV;
    for (int t = 0; t < SS; ++t) {
        float a0 = di, a1 = 0.f, a2 = 0.f, a3 = 0.f;
        #pragma unroll
        for (int j = 0; j < VV; j += 4) {
            a0 += wd[j] * __shfl(hd, j, 64);
            if (j + 1 < VV) a1 += wd[j + 1] * __shfl(hd, j + 1, 64);
            if (j + 2 < VV) a2 += wd[j + 2] * __shfl(hd, j + 2, 64);
            if (j + 3 < VV) a3 += wd[j + 3] * __shfl(hd, j + 3, 64);
        }
        float hn = fast_tanh((a0 + a1) + (a2 + a3));
        hd = hn;
        if (lane < VV) ob[t * VV + lane] = hn;
    }
}

extern "C" void kernel_launch(void* const* d_in, const int* in_sizes, int n_in,
                              void* d_out, int out_size, void* d_ws, size_t ws_size,
                              hipStream_t stream) {
    const float* x     = (const float*)d_in[0];
    const float* We_ih = (const float*)d_in[1];
    const float* We_hh = (const float*)d_in[2];
    const float* be_ih = (const float*)d_in[3];
    const float* be_hh = (const float*)d_in[4];
    const float* Wd_ih = (const float*)d_in[5];
    const float* Wd_hh = (const float*)d_in[6];
    const float* bd_ih = (const float*)d_in[7];
    const float* bd_hh = (const float*)d_in[8];
    float* out = (float*)d_out;

    rnn_fused<<<dim3(BB), dim3(256), 0, stream>>>(
        x, We_ih, We_hh, be_ih, be_hh, Wd_ih, Wd_hh, bd_ih, bd_hh, out);
}